// Round 10
// baseline (237.803 us; speedup 1.0000x reference)
//
#include <hip/hip_runtime.h>
#include <stdint.h>

#define TT 512
#define BB 32
#define EE 512
#define HH 2048

typedef __attribute__((ext_vector_type(8))) short short8;   // 8 x bf16 (4 VGPRs)
typedef __attribute__((ext_vector_type(4))) float f32x4;    // MFMA accumulator

// LDS geometry (in shorts)
#define XROW 528            // 512 data + 16 pad: measured 0 bank conflicts;
                            // 520 gave 8.4M conflicts. Row stride 1056 B.
#define XBUF (16 * XROW)    // one 16-t chunk buffer = 8448 shorts (16.5 KB)

static __device__ __forceinline__ float fast_exp(float x) {
    return __builtin_amdgcn_exp2f(x * 1.44269504f);
}
static __device__ __forceinline__ float fast_rcp(float x) {
    return __builtin_amdgcn_rcpf(x);
}

// Packed fp32->bf16 RNE convert: 1 instr per 2 elements.
static __device__ __forceinline__ unsigned cvtpk_bf16(float lo, float hi) {
    unsigned r;
    asm("v_cvt_pk_bf16_f32 %0, %1, %2" : "=v"(r) : "v"(lo), "v"(hi));
    return r;
}

// Async global->LDS DMA, 16 B/lane (wave-uniform LDS base + lane*16).
static __device__ __forceinline__ void load_lds16(const unsigned short* g, unsigned short* l) {
    __builtin_amdgcn_global_load_lds(
        (const __attribute__((address_space(1))) unsigned int*)(uintptr_t)g,
        (__attribute__((address_space(3))) unsigned int*)(uintptr_t)l,
        16, 0, 0);
}

// ---------------------------------------------------------------------------
// Pre-kernel (R9-verified): BW-optimal convert. Block-uniform X/W partition,
// 16 elems/thread, exact cover, max occupancy.
// ---------------------------------------------------------------------------
__launch_bounds__(256, 8)
__global__ void convert_inputs(const float* __restrict__ X,
                               const float* __restrict__ W,
                               unsigned short* __restrict__ Xb,
                               unsigned short* __restrict__ Wb) {
    // X: 8,388,608 elems = 2048 blocks * 4096; W: 3,145,728 = 768 blocks.
    const int bid = blockIdx.x;
    const float* src;
    unsigned short* dst;
    size_t base;
    if (bid < 2048) { src = X; dst = Xb; base = (size_t)bid * 4096; }
    else            { src = W; dst = Wb; base = (size_t)(bid - 2048) * 4096; }
    size_t j = base + (size_t)threadIdx.x * 16;

    float4 v0 = *(const float4*)(src + j);
    float4 v1 = *(const float4*)(src + j + 4);
    float4 v2 = *(const float4*)(src + j + 8);
    float4 v3 = *(const float4*)(src + j + 12);
    union { short8 s; unsigned u[4]; } o0, o1;
    o0.u[0] = cvtpk_bf16(v0.x, v0.y);
    o0.u[1] = cvtpk_bf16(v0.z, v0.w);
    o0.u[2] = cvtpk_bf16(v1.x, v1.y);
    o0.u[3] = cvtpk_bf16(v1.z, v1.w);
    o1.u[0] = cvtpk_bf16(v2.x, v2.y);
    o1.u[1] = cvtpk_bf16(v2.z, v2.w);
    o1.u[2] = cvtpk_bf16(v3.x, v3.y);
    o1.u[3] = cvtpk_bf16(v3.z, v3.w);
    *(short8*)(dst + j)     = o0.s;
    *(short8*)(dst + j + 8) = o1.s;
}

// ---------------------------------------------------------------------------
// Fused QRNN kernel — R13: GATE-SPLIT wave specialization (no k-split).
//
// R9 closed two theories: setprio neutral; the ~60us bench-qrnn gap is a
// harness floor (BW-optimal convert left it unchanged). The 172us plateau is
// issue-bound on the s=0 wave (~230 instrs/region incl. k-half exchange).
// The k-split existed only because 16h x full-K W = 192 regs; its tax is the
// exchange + a second MFMA wave per output.
//
// New structure: block = 16 h, 4 waves:
//   - 3 GATE waves: one gate each (z/f/o), FULL K=512. W = 16 frags = 64
//     AGPR. Per region: 16 ds_read_b128 + 16 MFMA (2 chains of 8) + ONE
//     f32x4 publish. ~48 instrs.
//   - 1 SCAN wave: no W. Per region: 3 ds_read_b128 (one stride-12 row:
//     conflict-free), bias add, full do_tail (activations + scan + carry +
//     vmax). ~130 instrs — the new (halved) barrier straggler.
// Scan role rotates with (slot&3) so co-resident blocks' scan waves sit on
// different SIMDs. Regs ~75 VGPR + 64 AGPR -> launch_bounds(256,3): 3
// blocks/CU (12 waves). Grid 4096 = 8 xcd x 4 b x 128 hgrp (16h each).
//
// Hazards:
//  (1) gates publish(ch) -> scan reads(ch) NEXT region: __syncthreads(ch)
//      (lgkm drained). Slot ch&1 republished region ch+2; scan's reads
//      retired at barrier(ch+1).
//  (2) X dbuf WAR/RAW: stage(ch+1) in region ch, consumed region ch+1;
//      vmcnt+lgkm drained at each __syncthreads (R1-verified pattern).
//  (3) Barriers wave-uniform (ch uniform; role branches contain no barrier).
//  (4) carry/vmax private to the scan wave; gates carry no state.
// ---------------------------------------------------------------------------
__launch_bounds__(256, 3)
__global__ void qrnn_fused(const unsigned short* __restrict__ Xb, // bf16 (T,B,E)
                           const unsigned short* __restrict__ Wb, // bf16 (3H,E)
                           const float* __restrict__ bias,        // (3H)
                           float* __restrict__ out)               // (B,H) fp32
{
    __shared__ unsigned short xlds[2 * XBUF];      // 33,792 B
    __shared__ float exch[2][64][12];              //  6,144 B (total 39,936 B)
    // exch row stride 12 floats = 48 B: bank-start 12L mod 32 bijective per
    // 8 lanes -> conflict-free b128 (same trick as the verified [64][12]).
    // Gate g occupies floats [4g..4g+3] of its lane row.

    const int tid  = threadIdx.x;
    const int wv   = tid >> 6;         // wave 0..3
    const int lane = tid & 63;
    const int q    = lane >> 4;        // quad 0..3
    const int c    = lane & 15;        // column within 16x16 tile (= h, = t)

    // XCD-aware swizzle: 4096 blocks = 8 XCDs x 4 batches x 128 h-groups.
    const int id   = blockIdx.x;       // 0..4095
    const int xcd  = id & 7;
    const int slot = id >> 3;          // 0..511 within this XCD
    const int b    = xcd * 4 + (slot >> 7);   // 4 batches per XCD
    const int hgrp = slot & 127;              // 128 h-groups (16 h) per batch
    const int h    = hgrp * 16 + c;

    // Role assignment: scan wave rotates by slot so co-resident blocks
    // (consecutive slots on one XCD) put scan waves on different SIMDs.
    const int  scanwv = slot & 3;
    const bool isScan = (wv == scanwv);
    const int  gsel   = (wv < scanwv) ? wv : wv - 1;   // 0..2 for gate waves

    float carry = 0.0f;    // scan wave only
    float vmax  = -1e30f;  // scan wave only
    float b0 = 0.f, b1 = 0.f, b2 = 0.f;

    // ---- gate waves: preload this gate's FULL-K W row-frags; pin in AGPR --
    short8 wg[16];
    if (!isScan) {
        const unsigned short* wr = Wb + ((size_t)gsel * HH + h) * EE;
#pragma unroll
        for (int k = 0; k < 16; ++k)
            wg[k] = *(const short8*)(wr + k * 32 + q * 8);
#pragma unroll
        for (int k = 0; k < 16; ++k)
            asm volatile("" : "+a"(wg[k]));
    } else {
        b0 = bias[h];
        b1 = bias[HH + h];
        b2 = bias[2 * HH + h];
    }

    // ---- staging: wave wv owns rows wv*4 .. wv*4+3 of each 16-t chunk ----
    const unsigned short* g0 = Xb + ((size_t)(wv * 4) * BB + b) * EE + lane * 8;
    unsigned short* l0 = &xlds[(wv * 4) * XROW];

    auto stage = [&](int n, int slt) {
        const unsigned short* g = g0 + (size_t)n * (16 * BB * EE);
        unsigned short* l = l0 + slt * XBUF;
#pragma unroll
        for (int i = 0; i < 4; ++i)
            load_lds16(g + (size_t)i * (BB * EE), l + i * XROW);
    };

    // tail (scan wave): activations + 16-step affine scan + carry + max.
    // Verbatim R1-verified math; inputs already bias-added.
    auto do_tail = [&](f32x4 az, f32x4 af, f32x4 ao) {
        float aa[4], mm[4], oo[4];
#pragma unroll
        for (int r = 0; r < 4; ++r) {
            float e2 = fast_exp(2.0f * az[r]);
            float z  = 1.0f - 2.0f * fast_rcp(e2 + 1.0f);  // tanh
            float f  = fast_rcp(1.0f + fast_exp(-af[r]));  // sigmoid
            float o  = fast_rcp(1.0f + fast_exp(-ao[r]));  // sigmoid
            aa[r] = f * z;
            mm[r] = 1.0f - f;
            oo[r] = o;
        }

        float A = aa[0], M = mm[0];
#pragma unroll
        for (int r = 1; r < 4; ++r) { A = aa[r] + mm[r] * A; M = mm[r] * M; }

        float Ap = __shfl_up(A, 16, 64), Mp = __shfl_up(M, 16, 64);
        if (q >= 1) { A = A + M * Ap; M = M * Mp; }
        Ap = __shfl_up(A, 32, 64); Mp = __shfl_up(M, 32, 64);
        if (q >= 2) { A = A + M * Ap; M = M * Mp; }
        float Ae = __shfl_up(A, 16, 64), Me = __shfl_up(M, 16, 64);
        if (q == 0) { Ae = 0.0f; Me = 1.0f; }
        float cc = Ae + Me * carry;

#pragma unroll
        for (int r = 0; r < 4; ++r) {
            cc = aa[r] + mm[r] * cc;
            vmax = fmaxf(vmax, oo[r] * cc);
        }

        float cend = A + M * carry;
        carry = __shfl(cend, 48 + c, 64);
    };

    stage(0, 0);
    __syncthreads();

    for (int ch = 0; ch < 32; ++ch) {
        const int buf = ch & 1;
        if (ch < 31) stage(ch + 1, buf ^ 1);

        if (!isScan) {
            // ---- gate wave: 16 MFMAs full-K for chunk ch, 2 chains ----
            const unsigned short* Abase = &xlds[buf * XBUF + c * XROW + q * 8];
            f32x4 ac0 = {0.f, 0.f, 0.f, 0.f};
            f32x4 ac1 = {0.f, 0.f, 0.f, 0.f};
#pragma unroll
            for (int half = 0; half < 2; ++half) {
                short8 a[8];
#pragma unroll
                for (int j = 0; j < 8; ++j)
                    a[j] = *(const short8*)(Abase + (half * 8 + j) * 32);
#pragma unroll
                for (int j = 0; j < 8; ++j) {
                    if (j & 1)
                        ac1 = __builtin_amdgcn_mfma_f32_16x16x32_bf16(a[j], wg[half * 8 + j], ac1, 0, 0, 0);
                    else
                        ac0 = __builtin_amdgcn_mfma_f32_16x16x32_bf16(a[j], wg[half * 8 + j], ac0, 0, 0, 0);
                }
            }
            f32x4 ac = ac0 + ac1;
            // publish into this chunk's ping-pong slot (floats 4g..4g+3)
            *(f32x4*)(&exch[ch & 1][lane][gsel * 4]) = ac;
        } else {
            // ---- scan wave: tail(ch-1) from exch slot (ch-1)&1 ----
            if (ch > 0) {
                const float* e = &exch[(ch - 1) & 1][lane][0];
                f32x4 az = *(const f32x4*)(e);
                f32x4 af = *(const f32x4*)(e + 4);
                f32x4 ao = *(const f32x4*)(e + 8);
#pragma unroll
                for (int r = 0; r < 4; ++r) { az[r] += b0; af[r] += b1; ao[r] += b2; }
                do_tail(az, af, ao);
            }
        }

        __syncthreads();   // the ONE barrier per region (hazards 1-3)
    }

    // ---- epilogue: tail(31) (published in region 31, ordered by its
    //      barrier), then output ----
    if (isScan) {
        const float* e = &exch[31 & 1][lane][0];
        f32x4 az = *(const f32x4*)(e);
        f32x4 af = *(const f32x4*)(e + 4);
        f32x4 ao = *(const f32x4*)(e + 8);
#pragma unroll
        for (int r = 0; r < 4; ++r) { az[r] += b0; af[r] += b1; ao[r] += b2; }
        do_tail(az, af, ao);

        vmax = fmaxf(vmax, __shfl_xor(vmax, 16, 64));
        vmax = fmaxf(vmax, __shfl_xor(vmax, 32, 64));
        if (q == 0) out[(size_t)b * HH + h] = vmax;
    }
}

// ---------------------------------------------------------------------------
extern "C" void kernel_launch(void* const* d_in, const int* in_sizes, int n_in,
                              void* d_out, int out_size, void* d_ws, size_t ws_size,
                              hipStream_t stream) {
    const float* sent = (const float*)d_in[0];
    // d_in[1] = lengths (unused by the math)
    const float* W    = (const float*)d_in[2];
    const float* bias = (const float*)d_in[3];
    float* out        = (float*)d_out;

    const int nX = TT * BB * EE;        // 8,388,608
    unsigned short* Xb = (unsigned short*)d_ws;
    unsigned short* Wb = Xb + nX;       // 16 MiB offset, 16B-aligned

    // X: 2048 blocks, W: 768 blocks (4096 elems each, exact cover)
    convert_inputs<<<2816, 256, 0, stream>>>(sent, W, Xb, Wb);

    dim3 grid(4096);                    // 8 xcd x 4 b x 128 hgrp (16 h each)
    qrnn_fused<<<grid, 256, 0, stream>>>(Xb, Wb, bias, out);
}